// Round 14
// baseline (23.869 us; speedup 1.0000x reference)
//
#include <hip/hip_runtime.h>
#include <hip/hip_bf16.h>

// MoE: out[b] = inp[b] @ weight[gate[b]].T
// inp: [4096,512] f32, gate: [4096] int, weight: [32,512,512] f32, out: [4096,512] f32
// Round 14: r13 direction continued to NKT=2 (BK=256): 3 barriers + 2 lgkm drains
// per block (r13: 8+4). COMPUTE per tile = 32 MFMA/wave, covering the A-gather
// (issued pre-half-1) and W stream (issued pre-half-2) at depth-1 with pin fences
// (r10-proven). TMAX=3 (max cnt<=192, +5.8 sigma, fixed dataset), W-first WRITE.

#define NE     32
#define NBATCH 4096
#define KF     512
#define NF     512
#define BM     64
#define BN     64
#define BK     256
#define TMAX   3
#define NCHUNK 64
#define NWG    (8 * NE * TMAX)  // 768, %8==0 -> bijective XCD swizzle

typedef __attribute__((ext_vector_type(8))) short bf16x8;
typedef __attribute__((ext_vector_type(4))) float f32x4;

__device__ __forceinline__ unsigned cvt2(float lo, float hi) {
    __hip_bfloat162 h = __float22bfloat162_rn(make_float2(lo, hi));
    return *reinterpret_cast<unsigned*>(&h);   // v_cvt_pk_bf16_f32
}

// XOR swizzle within [row][256 bf16] (512B row stride); same bijection write+read.
// Reads: 16 lanes x rows r..r+15 at same kb -> 8 distinct 16B slots -> 2-way (free).
__device__ __forceinline__ int swzr(int row, int col_b) {
    return row * 512 + (col_b ^ ((row & 7) << 4));
}

__global__ __launch_bounds__(256, 2)
void moe_fused(const float* __restrict__ inp,
               const int* __restrict__ gate,
               const float* __restrict__ weight,
               float* __restrict__ out) {
    // bijective XCD-chunk swizzle (768 blocks, 8 XCDs, 96/chunk): XCD k owns
    // experts [4k,4k+4) -> its W panels (~4MB) + token rows pinned in that L2.
    const int bid = blockIdx.x;
    const int swb = (bid & 7) * (NWG / 8) + (bid >> 3);
    const int nb    = swb & 7;
    const int y     = swb >> 3;          // 0..95
    const int e     = y / 3;
    const int local = y - e * 3;

    __shared__ __align__(16) unsigned char lds[(BM + BN) * BK * 2]; // A@0 32KB, W@32768 32KB
    __shared__ int srow[BM];
    __shared__ int chunkinfo[NCHUNK];
    __shared__ int stotal;

    const int tid  = threadIdx.x;
    const int lane = tid & 63;
    const int wid  = tid >> 6;

    // staging map: i=0..15 -> row = 4*i+wid (one full 256-float row per wave-instr),
    // col4 = (tid&63)*4
    const int c4   = (tid & 63) * 4;
    const int nblk = nb * BN;
    const float* wbase = weight + (size_t)e * (NF * KF) + (size_t)nblk * KF;
    const float* wrp   = wbase + (size_t)wid * KF + c4;   // + i*2048 floats per i

    float4 ra[16], rw[16];

    // ---- W tile-0 issued BEFORE prep (needs only e); drains under ballots ----
#pragma unroll
    for (int i = 0; i < 16; ++i) rw[i] = *(const float4*)(wrp + i * 2048);
    asm volatile("" ::: "memory");       // pin: don't sink into prep

    // ---- self-prep: ballot-rank tokens of expert e (r6/r10-proven) ----
    int g[16];
#pragma unroll
    for (int i = 0; i < 16; ++i)
        g[i] = gate[(wid * 16 + i) * 64 + lane];
#pragma unroll
    for (int i = 0; i < 16; ++i) {
        unsigned long long m = __ballot(g[i] == e);
        if (lane == i) chunkinfo[wid * 16 + i] = __popcll(m);
    }
    if (tid < BM) srow[tid] = -1;
    __syncthreads();
    if (tid < NCHUNK) {
        int c = chunkinfo[tid];
        int x = c;
#pragma unroll
        for (int d = 1; d < 64; d <<= 1) {
            int u = __shfl_up(x, d, 64);
            if (lane >= d) x += u;
        }
        chunkinfo[tid] = x - c;
        if (tid == NCHUNK - 1) stotal = x;
    }
    __syncthreads();

    const int total = stotal;
    const int m0    = local * BM;
    if (m0 >= total) return;             // uniform exit before any raw s_barrier

#pragma unroll
    for (int i = 0; i < 16; ++i) {
        unsigned long long m = __ballot(g[i] == e);
        int r = chunkinfo[wid * 16 + i] + __popcll(m & ((1ull << lane) - 1ull));
        if (g[i] == e && r >= m0 && r < m0 + BM)
            srow[r - m0] = (wid * 16 + i) * 64 + lane;
    }
    __syncthreads();

    const int wm = wid & 1;
    const int wn = wid >> 1;

    int arow[16];                        // clamped gather rows (row 0 = real data;
#pragma unroll                           //  padding outputs are never stored)
    for (int i = 0; i < 16; ++i) {
        int r = srow[4 * i + wid];
        arow[i] = (r < 0) ? 0 : r;
    }

#define LOADA(T) do { const int k0 = (T) * BK;                                       \
    _Pragma("unroll") for (int i = 0; i < 16; ++i)                                   \
        ra[i] = *(const float4*)(inp + (size_t)arow[i] * KF + k0 + c4); } while (0)

#define LOADW(T) do { const int k0 = (T) * BK;                                       \
    _Pragma("unroll") for (int i = 0; i < 16; ++i)                                   \
        rw[i] = *(const float4*)(wrp + i * 2048 + k0); } while (0)

// W written first (regs ready since prep); A's vmcnt drain overlaps the W ds_writes
#define WRITE_TILE() do { const int cb = (tid & 63) * 8;                             \
    _Pragma("unroll") for (int i = 0; i < 16; ++i) {                                 \
        int r = 4 * i + wid;                                                         \
        uint2 p = make_uint2(cvt2(rw[i].x, rw[i].y), cvt2(rw[i].z, rw[i].w));        \
        *(uint2*)(lds + 32768 + swzr(r, cb)) = p; }                                  \
    _Pragma("unroll") for (int i = 0; i < 16; ++i) {                                 \
        int r = 4 * i + wid;                                                         \
        uint2 p = make_uint2(cvt2(ra[i].x, ra[i].y), cvt2(ra[i].z, ra[i].w));        \
        *(uint2*)(lds + swzr(r, cb)) = p; } } while (0)

    f32x4 acc[2][2];
#pragma unroll
    for (int mi = 0; mi < 2; ++mi)
#pragma unroll
        for (int ni = 0; ni < 2; ++ni) acc[mi][ni] = (f32x4)(0.f);

#define COMPUTE_K(K0, K1) do {                                                       \
    _Pragma("unroll") for (int kk = (K0); kk < (K1); ++kk) {                         \
        const int kb = kk * 64 + 16 * (lane >> 4);                                   \
        bf16x8 af[2], bfr[2];                                                        \
        _Pragma("unroll") for (int mi = 0; mi < 2; ++mi) {                           \
            int r = wm * 32 + mi * 16 + (lane & 15);                                 \
            af[mi] = *(const bf16x8*)(lds + swzr(r, kb)); }                          \
        _Pragma("unroll") for (int ni = 0; ni < 2; ++ni) {                           \
            int r = wn * 32 + ni * 16 + (lane & 15);                                 \
            bfr[ni] = *(const bf16x8*)(lds + 32768 + swzr(r, kb)); }                 \
        _Pragma("unroll") for (int mi = 0; mi < 2; ++mi)                             \
        _Pragma("unroll") for (int ni = 0; ni < 2; ++ni)                             \
            acc[mi][ni] = __builtin_amdgcn_mfma_f32_16x16x32_bf16(                   \
                af[mi], bfr[ni], acc[mi][ni], 0, 0, 0); } } while (0)

    // ---- NKT=2 schedule: 3 barriers, 2 lgkm drains, depth-1 pinned loads ----
    LOADA(0);
    asm volatile("" ::: "memory");
    WRITE_TILE();                        // tile 0 -> LDS
    asm volatile("s_waitcnt lgkmcnt(0)" ::: "memory");
    __builtin_amdgcn_s_barrier();        // tile 0 ready

    LOADA(1);                            // A-gather: ~700cy of COMPUTE cover
    asm volatile("" ::: "memory");
    COMPUTE_K(0, 4);
    LOADW(1);                            // W stream: ~350cy cover (L2-resident)
    asm volatile("" ::: "memory");
    COMPUTE_K(4, 8);
    asm volatile("" ::: "memory");
    __builtin_amdgcn_s_barrier();        // all reads of tile 0 done

    WRITE_TILE();                        // tile 1 (vmcnt waits loads(1), covered)
    asm volatile("s_waitcnt lgkmcnt(0)" ::: "memory");
    __builtin_amdgcn_s_barrier();        // tile 1 ready
    COMPUTE_K(0, 8);
#undef LOADA
#undef LOADW
#undef WRITE_TILE
#undef COMPUTE_K

    // ---- epilogue: D frag col=lane&15 (n), row=(lane>>4)*4+q (m) ----
#pragma unroll
    for (int mi = 0; mi < 2; ++mi)
#pragma unroll
        for (int q = 0; q < 4; ++q) {
            int m = wm * 32 + mi * 16 + (lane >> 4) * 4 + q;
            int row = srow[m];
            if (row >= 0) {
#pragma unroll
                for (int ni = 0; ni < 2; ++ni)
                    out[(size_t)row * NF + nblk + wn * 32 + ni * 16 + (lane & 15)]
                        = acc[mi][ni][q];
            }
        }
}

extern "C" void kernel_launch(void* const* d_in, const int* in_sizes, int n_in,
                              void* d_out, int out_size, void* d_ws, size_t ws_size,
                              hipStream_t stream) {
    const float* inp    = (const float*)d_in[0];
    const int*   gate   = (const int*)d_in[1];
    const float* weight = (const float*)d_in[2];
    float*       out    = (float*)d_out;

    moe_fused<<<NWG, 256, 0, stream>>>(inp, gate, weight, out);
}

// Round 15
// 19.058 us; speedup vs baseline: 1.2524x; 1.2524x over previous
//
#include <hip/hip_runtime.h>
#include <hip/hip_bf16.h>

// MoE: out[b] = inp[b] @ weight[gate[b]].T
// inp: [4096,512] f32, gate: [4096] int, weight: [32,512,512] f32, out: [4096,512] f32
// Round 15: r13 (best, 19.2us) + (a) TMAX=3 (grid 768, r14-validated mapping) and
// (b) loads(t+1) issued BEFORE the lgkm drain + barrier (global loads legally fly
// across s_barrier; adds drain+sync time to the prefetch cover window).
// Everything else r13-verbatim: BK=128/NKT=4, depth-1 pinned prefetch, cvt_pk
// staging, XOR-swizzle both sides, 2 barriers/iter, W tile-0 before prep.

#define NE     32
#define NBATCH 4096
#define KF     512
#define NF     512
#define BM     64
#define BN     64
#define BK     128
#define NKT    (KF / BK)     // 4
#define TMAX   3
#define NCHUNK 64
#define NWG    (8 * NE * TMAX)  // 768, %8==0 -> bijective XCD swizzle

typedef __attribute__((ext_vector_type(8))) short bf16x8;
typedef __attribute__((ext_vector_type(4))) float f32x4;

__device__ __forceinline__ unsigned cvt2(float lo, float hi) {
    __hip_bfloat162 h = __float22bfloat162_rn(make_float2(lo, hi));
    return *reinterpret_cast<unsigned*>(&h);   // v_cvt_pk_bf16_f32
}

// XOR swizzle within [row][128 bf16] (256B row stride); same bijection write+read.
__device__ __forceinline__ int swz(int row, int col_b) {
    return (row * 256 + col_b) ^ ((row & 7) << 4);
}

__global__ __launch_bounds__(256)
void moe_fused(const float* __restrict__ inp,
               const int* __restrict__ gate,
               const float* __restrict__ weight,
               float* __restrict__ out) {
    // bijective XCD-chunk swizzle (768 blocks, 8 XCDs, 96/chunk): XCD k owns
    // experts [4k,4k+4) -> W panels + token rows pinned in that L2.
    const int bid = blockIdx.x;
    const int swb = (bid & 7) * (NWG / 8) + (bid >> 3);
    const int nb    = swb & 7;
    const int y     = swb >> 3;          // 0..95
    const int e     = y / 3;
    const int local = y - e * 3;

    __shared__ __align__(16) unsigned char lds[(BM + BN) * BK * 2]; // 32KB single buf
    __shared__ int srow[BM];
    __shared__ int chunkinfo[NCHUNK];
    __shared__ int stotal;

    const int tid  = threadIdx.x;
    const int lane = tid & 63;
    const int wid  = tid >> 6;

    // staging map: slot s = i*256+tid -> row = (tid>>5) + 8*i, col4 = (tid&31)*4
    const int srow_i = tid >> 5;
    const int c4     = (tid & 31) * 4;
    const int nblk   = nb * BN;
    const float* wbase = weight + (size_t)e * (NF * KF) + (size_t)nblk * KF;

    float4 ra[8], rw[8];

    // ---- W tile-0 issued BEFORE prep: only needs e; latency hides under ballots ----
#pragma unroll
    for (int i = 0; i < 8; ++i) {
        int r = srow_i + 8 * i;
        rw[i] = *(const float4*)(wbase + (size_t)r * KF + c4);
    }
    asm volatile("" ::: "memory");       // pin: issue now, don't sink into prep

    // ---- self-prep: ballot-rank tokens of expert e (r6/r10-proven) ----
    int g[16];
#pragma unroll
    for (int i = 0; i < 16; ++i)
        g[i] = gate[(wid * 16 + i) * 64 + lane];
#pragma unroll
    for (int i = 0; i < 16; ++i) {
        unsigned long long m = __ballot(g[i] == e);
        if (lane == i) chunkinfo[wid * 16 + i] = __popcll(m);
    }
    if (tid < BM) srow[tid] = -1;
    __syncthreads();
    if (tid < NCHUNK) {
        int c = chunkinfo[tid];
        int x = c;
#pragma unroll
        for (int d = 1; d < 64; d <<= 1) {
            int u = __shfl_up(x, d, 64);
            if (lane >= d) x += u;
        }
        chunkinfo[tid] = x - c;
        if (tid == NCHUNK - 1) stotal = x;
    }
    __syncthreads();

    const int total = stotal;
    const int m0    = local * BM;
    if (m0 >= total) return;             // uniform exit before any raw s_barrier

#pragma unroll
    for (int i = 0; i < 16; ++i) {
        unsigned long long m = __ballot(g[i] == e);
        int r = chunkinfo[wid * 16 + i] + __popcll(m & ((1ull << lane) - 1ull));
        if (g[i] == e && r >= m0 && r < m0 + BM)
            srow[r - m0] = (wid * 16 + i) * 64 + lane;
    }
    __syncthreads();

    const int wm = wid & 1;
    const int wn = wid >> 1;

    int arow[8];
    const float* ap[8];
#pragma unroll
    for (int i = 0; i < 8; ++i) {
        arow[i] = srow[srow_i + 8 * i];
        ap[i] = inp + (size_t)(arow[i] < 0 ? 0 : arow[i]) * KF + c4;
    }

#define LOADA(T) do { const int k0 = (T) * BK;                                       \
    _Pragma("unroll") for (int i = 0; i < 8; ++i)                                    \
        ra[i] = (arow[i] >= 0) ? *(const float4*)(ap[i] + k0)                        \
                               : make_float4(0.f, 0.f, 0.f, 0.f); } while (0)

#define LOADW(T) do { const int k0 = (T) * BK;                                       \
    _Pragma("unroll") for (int i = 0; i < 8; ++i) {                                  \
        int r = srow_i + 8 * i;                                                      \
        rw[i] = *(const float4*)(wbase + (size_t)r * KF + k0 + c4); } } while (0)

#define WRITE_TILE() do { const int cb = (tid & 31) * 8;                             \
    _Pragma("unroll") for (int i = 0; i < 8; ++i) {                                  \
        int r = srow_i + 8 * i;                                                      \
        uint2 p = make_uint2(cvt2(ra[i].x, ra[i].y), cvt2(ra[i].z, ra[i].w));        \
        *(uint2*)(lds + swz(r, cb)) = p; }                                           \
    _Pragma("unroll") for (int i = 0; i < 8; ++i) {                                  \
        int r = srow_i + 8 * i;                                                      \
        uint2 p = make_uint2(cvt2(rw[i].x, rw[i].y), cvt2(rw[i].z, rw[i].w));        \
        *(uint2*)(lds + 16384 + swz(r, cb)) = p; } } while (0)

    f32x4 acc[2][2];
#pragma unroll
    for (int mi = 0; mi < 2; ++mi)
#pragma unroll
        for (int ni = 0; ni < 2; ++ni) acc[mi][ni] = (f32x4)(0.f);

#define COMPUTE() do {                                                               \
    _Pragma("unroll") for (int kk = 0; kk < 4; ++kk) {                               \
        const int kb = kk * 64 + 16 * (lane >> 4);                                   \
        bf16x8 af[2], bfr[2];                                                        \
        _Pragma("unroll") for (int mi = 0; mi < 2; ++mi) {                           \
            int r = wm * 32 + mi * 16 + (lane & 15);                                 \
            af[mi] = *(const bf16x8*)(lds + swz(r, kb)); }                           \
        _Pragma("unroll") for (int ni = 0; ni < 2; ++ni) {                           \
            int r = wn * 32 + ni * 16 + (lane & 15);                                 \
            bfr[ni] = *(const bf16x8*)(lds + 16384 + swz(r, kb)); }                  \
        _Pragma("unroll") for (int mi = 0; mi < 2; ++mi)                             \
        _Pragma("unroll") for (int ni = 0; ni < 2; ++ni)                             \
            acc[mi][ni] = __builtin_amdgcn_mfma_f32_16x16x32_bf16(                   \
                af[mi], bfr[ni], acc[mi][ni], 0, 0, 0); } } while (0)

    // ---- K-loop: loads(t+1) issued BEFORE drain+barrier (fly across); pinned
    //      above COMPUTE(t) by the lgkm asm's memory clobber + pin fence ----
    LOADA(0);                            // W tile 0 in flight since kernel entry
    for (int t = 0; t < NKT; ++t) {
        WRITE_TILE();                    // per-use vmcnt: waits tile-t loads only
        if (t + 1 < NKT) {
            LOADA(t + 1);                // issue BEFORE barrier: +~300cy cover
            LOADW(t + 1);
        }
        asm volatile("s_waitcnt lgkmcnt(0)" ::: "memory");
        __builtin_amdgcn_s_barrier();    // LDS tile t consistent (loads in flight)
        asm volatile("" ::: "memory");   // PIN: loads may not sink below
        COMPUTE();
        asm volatile("" ::: "memory");
        __builtin_amdgcn_s_barrier();    // all reads done before next WRITE
        asm volatile("" ::: "memory");
    }
#undef LOADA
#undef LOADW
#undef WRITE_TILE
#undef COMPUTE

    // ---- epilogue: D frag col=lane&15 (n), row=(lane>>4)*4+q (m) ----
#pragma unroll
    for (int mi = 0; mi < 2; ++mi)
#pragma unroll
        for (int q = 0; q < 4; ++q) {
            int m = wm * 32 + mi * 16 + (lane >> 4) * 4 + q;
            int row = srow[m];
            if (row >= 0) {
#pragma unroll
                for (int ni = 0; ni < 2; ++ni)
                    out[(size_t)row * NF + nblk + wn * 32 + ni * 16 + (lane & 15)]
                        = acc[mi][ni][q];
            }
        }
}

extern "C" void kernel_launch(void* const* d_in, const int* in_sizes, int n_in,
                              void* d_out, int out_size, void* d_ws, size_t ws_size,
                              hipStream_t stream) {
    const float* inp    = (const float*)d_in[0];
    const int*   gate   = (const int*)d_in[1];
    const float* weight = (const float*)d_in[2];
    float*       out    = (float*)d_out;

    moe_fused<<<NWG, 256, 0, stream>>>(inp, gate, weight, out);
}